// Round 10
// baseline (194.242 us; speedup 1.0000x reference)
//
#include <hip/hip_runtime.h>

// Self-attention fwd, B=2 N=2048 H=16 D=64, fp32 in/out, bf16 MFMA compute.
// Round 17: 3 waves/SIMD via register diet; staging stays in registers.
//   Session evidence: R12/R16 stall ~70% per wave with 2 waves/SIMD
//   (VALUBusy 31 + MfmaUtil 28, both low); ~220 unified regs (124 VGPR +
//   ~96 AGPR) caps 2 waves/SIMD (512-reg slot budget). R13 proved the LDS
//   hop costs more than a 3rd wave gains; R8 proved same-iteration C++
//   double-buffers collapse. This round gets the 3rd wave WITHOUT either:
//   * serial qt: one sacc live at a time (-16 AGPR)
//   * SINGLE-buffered kf/vf (-32 VGPR): refill is consumed NEXT iteration,
//     so even the latest compiler placement (right after last use) gives
//     ~280cy (K) / ~400cy (V) cover -> sink-tolerant by construction.
//   * 4-way ksel (R13's verified grid/indexing/epilogue): grid 1024,
//     16 tiles/wave, traffic unchanged 537 MB; 3-zone combine.
//   * __launch_bounds__(256,3); est. 86 VGPR + 80 AGPR = 166 <= 170.
//   Plain C++ loads only (never failed); no sched_barriers (R16: neutral).
//
// MFMA 32x32x16 bf16 layouts (HW-verified):
//   A: A[m=lane&31][k=(lane>>5)*8+j]   B: B[k=(lane>>5)*8+j][n=lane&31]
//   C/D: D[row=(reg&3)+8*(reg>>2)+4*(lane>>5)][col=lane&31]
//
// Kt tile (32 keys): block kc(0..3), lane l, j=0..7 holds
//   K[key=tile*32+(l&31)][d=kc*16+(l>>5)*8+j]          (S^T = K*Q^T A-frag)
// Vt tile: block qq=dt*2+s (0..3), lane l: j=0..3 ->
//   V[key=tile*32+8s+4g+j][d=dt*32+nl]; j=4..7 -> key 16+8s+4g+(j-4)
//   (matches P^T packing: k-slot {0-3,4-7} <-> keys {8s..,16+8s..} per g)

typedef float  f32x4  __attribute__((ext_vector_type(4)));
typedef float  f32x16 __attribute__((ext_vector_type(16)));
typedef short  s16x8  __attribute__((ext_vector_type(8)));
typedef short  s16x4  __attribute__((ext_vector_type(4)));
typedef int    i32x4  __attribute__((ext_vector_type(4)));

#define QSCALE 0.18033688011112042f  /* log2(e)/8 : folds 1/sqrt(64) + exp2 */

__device__ __forceinline__ unsigned short bf16r(float f) {
    unsigned u = __builtin_bit_cast(unsigned, f);
    u += 0x7fffu + ((u >> 16) & 1u);          // round-to-nearest-even
    return (unsigned short)(u >> 16);
}

__device__ __forceinline__ s16x8 cvt8f_scaled(const float* p, float s) {
    f32x4 a = *(const f32x4*)p;
    f32x4 b = *(const f32x4*)(p + 4);
    s16x8 r;
#pragma unroll
    for (int i = 0; i < 4; ++i) {
        r[i]   = (short)bf16r(a[i] * s);
        r[i+4] = (short)bf16r(b[i] * s);
    }
    return r;
}

// pack two f32 -> bf16 pair (lo in [15:0], hi in [31:16]), single VALU op
__device__ __forceinline__ int cvtpk2(float lo, float hi) {
    int r;
    asm("v_cvt_pk_bf16_f32 %0, %1, %2" : "=v"(r) : "v"(lo), "v"(hi));
    return r;
}

// ---- prepass: emit fragment-ordered bf16 tile images for K and V --------
// (identical to passing R9/R11/R12/R13/R16)
__global__ void __launch_bounds__(256)
prep(const float* __restrict__ K, const float* __restrict__ V,
     unsigned short* __restrict__ Kt, unsigned short* __restrict__ Vt) {
    const int t = threadIdx.x, bid = blockIdx.x;
    const int bh = bid & 31, nb = bid >> 5;      // nb: 2 tiles of 32 keys
    const int b = bh >> 4, h = bh & 15;
    const size_t tile0 = ((size_t)bh * 64 + nb * 2) * 2048;   // shorts

    // K: [tile][kc][lane][8] — lane reads 8 consecutive d of one key row
#pragma unroll
    for (int i = 0; i < 2; ++i) {
        const int lin = i * 256 + t;
        const int kbl = lin >> 8, rem = lin & 255;
        const int kc = rem >> 6, l = rem & 63;
        const int nl = l & 31, gg = l >> 5;
        const float* src = K + ((size_t)(b * 2048 + nb * 64 + kbl * 32 + nl)) * 1024
                             + h * 64 + kc * 16 + gg * 8;
        f32x4 a = *(const f32x4*)src;
        f32x4 c = *(const f32x4*)(src + 4);
        i32x4 o = { cvtpk2(a[0], a[1]), cvtpk2(a[2], a[3]),
                    cvtpk2(c[0], c[1]), cvtpk2(c[2], c[3]) };
        *(i32x4*)(Kt + tile0 + kbl * 2048 + kc * 512 + l * 8) = o;
    }

    // V: [tile][qq=dt*2+s][lane][8] — gather 8 keys at one d
#pragma unroll
    for (int i = 0; i < 2; ++i) {
        const int lin = i * 256 + t;
        const int kbl = lin >> 8, rem = lin & 255;
        const int qq = rem >> 6, l = rem & 63;
        const int dt = qq >> 1, s = qq & 1;
        const int nl = l & 31, gg = l >> 5;
        const float* vp0 = V + ((size_t)(b * 2048 + nb * 64 + kbl * 32 + 8 * s + 4 * gg)) * 1024
                             + h * 64 + dt * 32 + nl;
        float x0 = vp0[0],     x1 = vp0[1024],  x2 = vp0[2048],  x3 = vp0[3072];
        float x4 = vp0[16384], x5 = vp0[17408], x6 = vp0[18432], x7 = vp0[19456];
        i32x4 o = { cvtpk2(x0, x1), cvtpk2(x2, x3),
                    cvtpk2(x4, x5), cvtpk2(x6, x7) };
        *(i32x4*)(Vt + tile0 + kbl * 2048 + qq * 512 + l * 8) = o;
    }
}

// ---- main attention kernel ----------------------------------------------
// 1024 blocks x 4 waves. Block = 64 queries of head bh = bid&31
// (q0 = (bid>>5)*64); wave = key quarter ksel, 16 tiles of 32 keys.
// Same-bh blocks all land on XCD bh&7 -> 1 MB tile set per XCD L2.
__global__ void __launch_bounds__(256, 3)
attn_fwd(const float* __restrict__ Q, const unsigned short* __restrict__ Kt,
         const unsigned short* __restrict__ Vt, float* __restrict__ O)
{
    __shared__ __align__(16) float ex[3 * 64 * 68];   // 52224 B combine zones

    const int t = threadIdx.x;
    const int ksel = t >> 6, lane = t & 63;
    const int g = lane >> 5, nl = lane & 31;

    const int bid = blockIdx.x;
    const int bh  = bid & 31, qb = bid >> 5;
    const int b   = bh >> 4,  h  = bh & 15;
    const int q0  = qb * 64;

    // Q B-frags (pre-scaled by log2e/8): qf[qt][kc], q = q0 + qt*32 + nl
    s16x8 qf[2][4];
#pragma unroll
    for (int qt = 0; qt < 2; ++qt) {
        const float* qp = Q + ((size_t)(b * 2048 + q0 + qt * 32 + nl)) * 1024
                            + h * 64 + g * 8;
#pragma unroll
        for (int kc = 0; kc < 4; ++kc)
            qf[qt][kc] = cvt8f_scaled(qp + kc * 16, QSCALE);
    }

    // per-lane tile pointers (key quarter ksel: 16 tiles x 4KB each)
    const unsigned short* ka = Kt + (size_t)bh * 131072 + (size_t)ksel * 32768 + lane * 8;
    const unsigned short* va = Vt + (size_t)bh * 131072 + (size_t)ksel * 32768 + lane * 8;

    f32x16 oa00 = {}, oa01 = {}, oa10 = {}, oa11 = {};  // oa[dt][qt]
    f32x4  lpv0 = {}, lpv1 = {};

    s16x8 kf[4], vf[4];                          // SINGLE tile buffer each

    // prologue: tile 0 resident
#pragma unroll
    for (int i = 0; i < 4; ++i) {
        kf[i] = *(const s16x8*)(ka + i * 512);
        vf[i] = *(const s16x8*)(va + i * 512);
    }
    const unsigned short* kp = ka + 2048;        // next-tile pointers
    const unsigned short* vp = va + 2048;

#pragma unroll 1
    for (int it = 0; it < 16; ++it) {
        int pk0[8], pk1[8];

        // ---- QK qt0 + softmax qt0 (sacc live: 16 AGPR) ----
        {
            f32x16 sc = {};
            __builtin_amdgcn_s_setprio(1);
#pragma unroll
            for (int kc = 0; kc < 4; ++kc)
                sc = __builtin_amdgcn_mfma_f32_32x32x16_bf16(kf[kc], qf[0][kc], sc, 0, 0, 0);
            __builtin_amdgcn_s_setprio(0);
#pragma unroll
            for (int c = 0; c < 4; ++c) {
                f32x4 e = { __builtin_amdgcn_exp2f(sc[4*c]),
                            __builtin_amdgcn_exp2f(sc[4*c+1]),
                            __builtin_amdgcn_exp2f(sc[4*c+2]),
                            __builtin_amdgcn_exp2f(sc[4*c+3]) };
                lpv0 += e;
                pk0[2*c]   = cvtpk2(e[0], e[1]);
                pk0[2*c+1] = cvtpk2(e[2], e[3]);
            }
        }

        // ---- QK qt1 (last use of kf) + refill kf + softmax qt1 ----
        {
            f32x16 sc = {};
            __builtin_amdgcn_s_setprio(1);
#pragma unroll
            for (int kc = 0; kc < 4; ++kc)
                sc = __builtin_amdgcn_mfma_f32_32x32x16_bf16(kf[kc], qf[1][kc], sc, 0, 0, 0);
            __builtin_amdgcn_s_setprio(0);
            if (it < 15) {                       // kf dead: refill tile it+1
#pragma unroll
                for (int i = 0; i < 4; ++i)
                    kf[i] = *(const s16x8*)(kp + i * 512);
            }
#pragma unroll
            for (int c = 0; c < 4; ++c) {
                f32x4 e = { __builtin_amdgcn_exp2f(sc[4*c]),
                            __builtin_amdgcn_exp2f(sc[4*c+1]),
                            __builtin_amdgcn_exp2f(sc[4*c+2]),
                            __builtin_amdgcn_exp2f(sc[4*c+3]) };
                lpv1 += e;
                pk1[2*c]   = cvtpk2(e[0], e[1]);
                pk1[2*c+1] = cvtpk2(e[2], e[3]);
            }
        }

        // ---- PV both qt (last use of vf) ----
        __builtin_amdgcn_s_setprio(1);
#pragma unroll
        for (int s = 0; s < 2; ++s) {
            i32x4 b0 = { pk0[s*2], pk0[s*2+1], pk0[s*2+4], pk0[s*2+5] };
            i32x4 b1 = { pk1[s*2], pk1[s*2+1], pk1[s*2+4], pk1[s*2+5] };
            s16x8 bb0 = __builtin_bit_cast(s16x8, b0);
            s16x8 bb1 = __builtin_bit_cast(s16x8, b1);
            oa00 = __builtin_amdgcn_mfma_f32_32x32x16_bf16(vf[s],     bb0, oa00, 0, 0, 0);
            oa10 = __builtin_amdgcn_mfma_f32_32x32x16_bf16(vf[2 + s], bb0, oa10, 0, 0, 0);
            oa01 = __builtin_amdgcn_mfma_f32_32x32x16_bf16(vf[s],     bb1, oa01, 0, 0, 0);
            oa11 = __builtin_amdgcn_mfma_f32_32x32x16_bf16(vf[2 + s], bb1, oa11, 0, 0, 0);
        }
        __builtin_amdgcn_s_setprio(0);
        if (it < 15) {                           // vf dead: refill tile it+1
#pragma unroll
            for (int i = 0; i < 4; ++i)
                vf[i] = *(const s16x8*)(vp + i * 512);
            kp += 2048;
            vp += 2048;
        }
    }

    float lp[2] = { lpv0[0] + lpv0[1] + lpv0[2] + lpv0[3],
                    lpv1[0] + lpv1[1] + lpv1[2] + lpv1[3] };

    // ---- combine the 4 key quarters (R13 epilogue, verified) ----
    if (ksel) {
        float* zone = ex + (ksel - 1) * (64 * 68) + lane * 68;  // 272B stride
#pragma unroll
        for (int i = 0; i < 4; ++i) {
            *(f32x4*)(zone + i * 4) =
                (f32x4){ oa00[4*i], oa00[4*i+1], oa00[4*i+2], oa00[4*i+3] };
            *(f32x4*)(zone + 16 + i * 4) =
                (f32x4){ oa01[4*i], oa01[4*i+1], oa01[4*i+2], oa01[4*i+3] };
            *(f32x4*)(zone + 32 + i * 4) =
                (f32x4){ oa10[4*i], oa10[4*i+1], oa10[4*i+2], oa10[4*i+3] };
            *(f32x4*)(zone + 48 + i * 4) =
                (f32x4){ oa11[4*i], oa11[4*i+1], oa11[4*i+2], oa11[4*i+3] };
        }
        zone[64] = lp[0];
        zone[65] = lp[1];
    }
    __syncthreads();
    if (!ksel) {
        float lps0 = lp[0], lps1 = lp[1];
#pragma unroll
        for (int z = 0; z < 3; ++z) {
            const float* zn = ex + z * (64 * 68) + lane * 68;
#pragma unroll
            for (int i = 0; i < 4; ++i) {
                f32x4 u0 = *(const f32x4*)(zn + i * 4);
                f32x4 u1 = *(const f32x4*)(zn + 16 + i * 4);
                f32x4 u2 = *(const f32x4*)(zn + 32 + i * 4);
                f32x4 u3 = *(const f32x4*)(zn + 48 + i * 4);
#pragma unroll
                for (int j = 0; j < 4; ++j) {
                    oa00[4*i+j] += u0[j]; oa01[4*i+j] += u1[j];
                    oa10[4*i+j] += u2[j]; oa11[4*i+j] += u3[j];
                }
            }
            lps0 += zn[64];
            lps1 += zn[65];
        }
        float inv[2];
        {
            float ss0 = lps0 + __shfl_xor(lps0, 32);   // opposite g-half
            float ss1 = lps1 + __shfl_xor(lps1, 32);
            inv[0] = 1.0f / ss0;
            inv[1] = 1.0f / ss1;
        }
        float* op0 = O + ((size_t)(b * 2048 + q0 + nl)) * 1024 + h * 64;
        float* op1 = op0 + 32 * 1024;            // q0 + 32 + nl
#pragma unroll
        for (int rq = 0; rq < 4; ++rq) {
            const int d0 = 8 * rq + 4 * g;
            *(f32x4*)(op0 + d0) = (f32x4){
                oa00[4*rq]   * inv[0], oa00[4*rq+1] * inv[0],
                oa00[4*rq+2] * inv[0], oa00[4*rq+3] * inv[0] };
            *(f32x4*)(op0 + 32 + d0) = (f32x4){
                oa10[4*rq]   * inv[0], oa10[4*rq+1] * inv[0],
                oa10[4*rq+2] * inv[0], oa10[4*rq+3] * inv[0] };
            *(f32x4*)(op1 + d0) = (f32x4){
                oa01[4*rq]   * inv[1], oa01[4*rq+1] * inv[1],
                oa01[4*rq+2] * inv[1], oa01[4*rq+3] * inv[1] };
            *(f32x4*)(op1 + 32 + d0) = (f32x4){
                oa11[4*rq]   * inv[1], oa11[4*rq+1] * inv[1],
                oa11[4*rq+2] * inv[1], oa11[4*rq+3] * inv[1] };
        }
    }
}

extern "C" void kernel_launch(void* const* d_in, const int* in_sizes, int n_in,
                              void* d_out, int out_size, void* d_ws, size_t ws_size,
                              hipStream_t stream) {
    const float* q = (const float*)d_in[0];
    const float* k = (const float*)d_in[1];
    const float* v = (const float*)d_in[2];
    float* o = (float*)d_out;

    unsigned short* Kt = (unsigned short*)d_ws;   // 8 MB fragment-ordered K tiles
    unsigned short* Vt = Kt + 4194304;            // 8 MB fragment-ordered V tiles

    hipLaunchKernelGGL(prep,     dim3(1024), dim3(256), 0, stream, k, v, Kt, Vt);
    hipLaunchKernelGGL(attn_fwd, dim3(1024), dim3(256), 0, stream, q, Kt, Vt, o);
}

// Round 11
// 128.927 us; speedup vs baseline: 1.5066x; 1.5066x over previous
//
#include <hip/hip_runtime.h>

// Self-attention fwd, B=2 N=2048 H=16 D=64, fp32 in/out, bf16 MFMA compute.
// Round 18: serial-qt cross-unit software pipeline on R12 (best: 47.4 us).
//   Evidence trail: R12/R16 stall ~60% intra-wave (QK->exp2->PV strictly
//   serial per tile; VALU 31 + MFMA 27 at 2 waves/SIMD). R14/R15 broke the
//   serialization with cross-TILE skew but needed 4 live score stages
//   (+64 AGPR) -> register cliff (>~230 unified = miscompile/spill; R17
//   confirmed: (256,3) cap -> 60 MB scratch traffic, 130 us).
//   This round: skew at UNIT granularity (unit = one qt of one tile).
//   While unit u's exp2/pack+PV (VALU) runs, unit u+1's QK chain (MFMA)
//   runs -- independent, same scheduling region, NO fences. Serial-qt
//   needs only 2 live score regs (sE/sO) = exactly R12's existing s0/s1
//   budget: ~95 VGPR + 96 AGPR ~= 191 unified < R12's 220 << cliff.
//   Single kf/vf buffers: refill right after last use, next use >=600cy
//   later (R8-R11 proved compiler placement is fine). (256,2): no spill
//   possible at 191. Grid 512 / traffic 537 MB / epilogue / prep = R12.
//   WAR on sE/sO is safe under in-order issue: the overwriting QK issues
//   after the last exp2 reading that register has issued.
//
// MFMA 32x32x16 bf16 layouts (HW-verified):
//   A: A[m=lane&31][k=(lane>>5)*8+j]   B: B[k=(lane>>5)*8+j][n=lane&31]
//   C/D: D[row=(reg&3)+8*(reg>>2)+4*(lane>>5)][col=lane&31]
//
// Kt tile (32 keys): block kc(0..3), lane l, j=0..7 holds
//   K[key=tile*32+(l&31)][d=kc*16+(l>>5)*8+j]          (S^T = K*Q^T A-frag)
// Vt tile: block qq=dt*2+s (0..3), lane l: j=0..3 ->
//   V[key=tile*32+8s+4g+j][d=dt*32+nl]; j=4..7 -> key 16+8s+4g+(j-4)
//   (matches P^T packing: k-slot {0-3,4-7} <-> keys {8s..,16+8s..} per g)

typedef float  f32x4  __attribute__((ext_vector_type(4)));
typedef float  f32x16 __attribute__((ext_vector_type(16)));
typedef short  s16x8  __attribute__((ext_vector_type(8)));
typedef short  s16x4  __attribute__((ext_vector_type(4)));
typedef int    i32x4  __attribute__((ext_vector_type(4)));

#define QSCALE 0.18033688011112042f  /* log2(e)/8 : folds 1/sqrt(64) + exp2 */

__device__ __forceinline__ unsigned short bf16r(float f) {
    unsigned u = __builtin_bit_cast(unsigned, f);
    u += 0x7fffu + ((u >> 16) & 1u);          // round-to-nearest-even
    return (unsigned short)(u >> 16);
}

__device__ __forceinline__ s16x8 cvt8f_scaled(const float* p, float s) {
    f32x4 a = *(const f32x4*)p;
    f32x4 b = *(const f32x4*)(p + 4);
    s16x8 r;
#pragma unroll
    for (int i = 0; i < 4; ++i) {
        r[i]   = (short)bf16r(a[i] * s);
        r[i+4] = (short)bf16r(b[i] * s);
    }
    return r;
}

// pack two f32 -> bf16 pair (lo in [15:0], hi in [31:16]), single VALU op
__device__ __forceinline__ int cvtpk2(float lo, float hi) {
    int r;
    asm("v_cvt_pk_bf16_f32 %0, %1, %2" : "=v"(r) : "v"(lo), "v"(hi));
    return r;
}

// ---- prepass: emit fragment-ordered bf16 tile images for K and V --------
// (identical to passing R9/R11/R12/R16)
__global__ void __launch_bounds__(256)
prep(const float* __restrict__ K, const float* __restrict__ V,
     unsigned short* __restrict__ Kt, unsigned short* __restrict__ Vt) {
    const int t = threadIdx.x, bid = blockIdx.x;
    const int bh = bid & 31, nb = bid >> 5;      // nb: 2 tiles of 32 keys
    const int b = bh >> 4, h = bh & 15;
    const size_t tile0 = ((size_t)bh * 64 + nb * 2) * 2048;   // shorts

    // K: [tile][kc][lane][8] — lane reads 8 consecutive d of one key row
#pragma unroll
    for (int i = 0; i < 2; ++i) {
        const int lin = i * 256 + t;
        const int kbl = lin >> 8, rem = lin & 255;
        const int kc = rem >> 6, l = rem & 63;
        const int nl = l & 31, gg = l >> 5;
        const float* src = K + ((size_t)(b * 2048 + nb * 64 + kbl * 32 + nl)) * 1024
                             + h * 64 + kc * 16 + gg * 8;
        f32x4 a = *(const f32x4*)src;
        f32x4 c = *(const f32x4*)(src + 4);
        i32x4 o = { cvtpk2(a[0], a[1]), cvtpk2(a[2], a[3]),
                    cvtpk2(c[0], c[1]), cvtpk2(c[2], c[3]) };
        *(i32x4*)(Kt + tile0 + kbl * 2048 + kc * 512 + l * 8) = o;
    }

    // V: [tile][qq=dt*2+s][lane][8] — gather 8 keys at one d
#pragma unroll
    for (int i = 0; i < 2; ++i) {
        const int lin = i * 256 + t;
        const int kbl = lin >> 8, rem = lin & 255;
        const int qq = rem >> 6, l = rem & 63;
        const int dt = qq >> 1, s = qq & 1;
        const int nl = l & 31, gg = l >> 5;
        const float* vp0 = V + ((size_t)(b * 2048 + nb * 64 + kbl * 32 + 8 * s + 4 * gg)) * 1024
                             + h * 64 + dt * 32 + nl;
        float x0 = vp0[0],     x1 = vp0[1024],  x2 = vp0[2048],  x3 = vp0[3072];
        float x4 = vp0[16384], x5 = vp0[17408], x6 = vp0[18432], x7 = vp0[19456];
        i32x4 o = { cvtpk2(x0, x1), cvtpk2(x2, x3),
                    cvtpk2(x4, x5), cvtpk2(x6, x7) };
        *(i32x4*)(Vt + tile0 + kbl * 2048 + qq * 512 + l * 8) = o;
    }
}

// ---- main attention kernel ----------------------------------------------
// 512 blocks x 4 waves (qsel = w&1, ksel = w>>1). Wave = 64 queries
// (2 q-tiles of 32) x one key half (32 tiles of 32 keys).
__global__ void __launch_bounds__(256, 2)
attn_fwd(const float* __restrict__ Q, const unsigned short* __restrict__ Kt,
         const unsigned short* __restrict__ Vt, float* __restrict__ O)
{
    __shared__ __align__(16) float ex[2 * 64 * 68];   // 34.8 KB combine zones

    const int t = threadIdx.x;
    const int w = t >> 6, lane = t & 63;
    const int g = lane >> 5, nl = lane & 31;
    const int qsel = w & 1, ksel = w >> 1;

    const int bid = blockIdx.x;
    const int bh  = bid & 31, qb = bid >> 5;     // XCD = bid&7 = bh&7: 2MB/XCD
    const int b   = bh >> 4,  h  = bh & 15;
    const int q0  = qb * 128 + qsel * 64;

    // Q B-frags (pre-scaled by log2e/8): qf[qt][kc], q = q0 + qt*32 + nl
    s16x8 qf[2][4];
#pragma unroll
    for (int qt = 0; qt < 2; ++qt) {
        const float* qp = Q + ((size_t)(b * 2048 + q0 + qt * 32 + nl)) * 1024
                            + h * 64 + g * 8;
#pragma unroll
        for (int kc = 0; kc < 4; ++kc)
            qf[qt][kc] = cvt8f_scaled(qp + kc * 16, QSCALE);
    }

    // rolling per-lane tile pointers (advance 2048 shorts = 4KB per tile)
    const unsigned short* kp = Kt + (size_t)bh * 131072 + (size_t)ksel * 65536 + lane * 8;
    const unsigned short* vp = Vt + (size_t)bh * 131072 + (size_t)ksel * 65536 + lane * 8;

    f32x16 oa00 = {}, oa01 = {}, oa10 = {}, oa11 = {};  // oa[dt][qt]
    f32x16 sE, sO;                               // the ONLY 2 score stages
    f32x4  lpv0 = {}, lpv1 = {};

    s16x8 kf[4], vf[4];                          // single tile buffer each

#define QKCHAIN(DST, QFq) do {                                              \
        DST = (f32x16){};                                                   \
        __builtin_amdgcn_s_setprio(1);                                      \
        _Pragma("unroll")                                                   \
        for (int _kc = 0; _kc < 4; ++_kc)                                   \
            DST = __builtin_amdgcn_mfma_f32_32x32x16_bf16(                  \
                kf[_kc], QFq[_kc], DST, 0, 0, 0);                           \
        __builtin_amdgcn_s_setprio(0); } while (0)

#define EXPPK1(S, LPV, PK) do {                                             \
        _Pragma("unroll")                                                   \
        for (int _c = 0; _c < 4; ++_c) {                                    \
            f32x4 e = { __builtin_amdgcn_exp2f(S[4*_c]),                    \
                        __builtin_amdgcn_exp2f(S[4*_c+1]),                  \
                        __builtin_amdgcn_exp2f(S[4*_c+2]),                  \
                        __builtin_amdgcn_exp2f(S[4*_c+3]) };                \
            LPV += e;                                                       \
            PK[2*_c]   = cvtpk2(e[0], e[1]);                                \
            PK[2*_c+1] = cvtpk2(e[2], e[3]);                                \
        } } while (0)

#define PVQ(PK, OA0, OA1) do {                                              \
        __builtin_amdgcn_s_setprio(1);                                      \
        _Pragma("unroll")                                                   \
        for (int _s = 0; _s < 2; ++_s) {                                    \
            i32x4 bd = { PK[_s*2], PK[_s*2+1], PK[_s*2+4], PK[_s*2+5] };    \
            s16x8 bb = __builtin_bit_cast(s16x8, bd);                       \
            OA0 = __builtin_amdgcn_mfma_f32_32x32x16_bf16(vf[_s],     bb, OA0, 0, 0, 0); \
            OA1 = __builtin_amdgcn_mfma_f32_32x32x16_bf16(vf[2 + _s], bb, OA1, 0, 0, 0); \
        }                                                                   \
        __builtin_amdgcn_s_setprio(0); } while (0)

#define REFILL_K do {                                                       \
        _Pragma("unroll")                                                   \
        for (int _i = 0; _i < 4; ++_i)                                      \
            kf[_i] = *(const s16x8*)(kp + _i * 512); } while (0)
#define REFILL_V do {                                                       \
        _Pragma("unroll")                                                   \
        for (int _i = 0; _i < 4; ++_i)                                      \
            vf[_i] = *(const s16x8*)(vp + _i * 512); } while (0)

    // prologue: tile 0 resident; scores(tile0, qt0) -> sE
    REFILL_K;
    REFILL_V;
    kp += 2048;
    vp += 2048;
    QKCHAIN(sE, qf[0]);

#pragma unroll 1
    for (int m = 0; m < 31; ++m) {
        int pk[8];
        // unit 2m+1's producer: QK(tile m, qt1) -> sO  [kf(m) last use]
        QKCHAIN(sO, qf[1]);
        REFILL_K;                                // kf <- tile m+1
        kp += 2048;
        // finish unit 2m: exp2/pack(sE) + PV(tile m, qt0)  [VALU || QK drain]
        EXPPK1(sE, lpv0, pk);
        PVQ(pk, oa00, oa10);
        // unit 2m+2's producer: QK(tile m+1, qt0) -> sE  [kf just refilled]
        QKCHAIN(sE, qf[0]);
        // finish unit 2m+1: exp2/pack(sO) + PV(tile m, qt1)  [vf last use]
        EXPPK1(sO, lpv1, pk);
        PVQ(pk, oa01, oa11);
        REFILL_V;                                // vf <- tile m+1
        vp += 2048;
    }
    // tail: tile 31 (sE = scores(31, qt0); kf/vf hold tile 31)
    {
        int pk[8];
        QKCHAIN(sO, qf[1]);
        EXPPK1(sE, lpv0, pk);
        PVQ(pk, oa00, oa10);
        EXPPK1(sO, lpv1, pk);
        PVQ(pk, oa01, oa11);
    }

#undef QKCHAIN
#undef EXPPK1
#undef PVQ
#undef REFILL_K
#undef REFILL_V

    float lp[2] = { lpv0[0] + lpv0[1] + lpv0[2] + lpv0[3],
                    lpv1[0] + lpv1[1] + lpv1[2] + lpv1[3] };

    // ---- combine key halves (pure add; softmax is max-free) ----
    __syncthreads();                             // all waves done with tiles
    float* zone = ex + qsel * (64 * 68) + lane * 68;   // 272B stride: aligned
    if (ksel) {
#pragma unroll
        for (int i = 0; i < 4; ++i) {
            *(f32x4*)(zone + i * 4) =
                (f32x4){ oa00[4*i], oa00[4*i+1], oa00[4*i+2], oa00[4*i+3] };
            *(f32x4*)(zone + 16 + i * 4) =
                (f32x4){ oa01[4*i], oa01[4*i+1], oa01[4*i+2], oa01[4*i+3] };
            *(f32x4*)(zone + 32 + i * 4) =
                (f32x4){ oa10[4*i], oa10[4*i+1], oa10[4*i+2], oa10[4*i+3] };
            *(f32x4*)(zone + 48 + i * 4) =
                (f32x4){ oa11[4*i], oa11[4*i+1], oa11[4*i+2], oa11[4*i+3] };
        }
        zone[64] = lp[0];
        zone[65] = lp[1];
    }
    __syncthreads();
    if (!ksel) {
#pragma unroll
        for (int i = 0; i < 4; ++i) {
            f32x4 u0 = *(const f32x4*)(zone + i * 4);
            f32x4 u1 = *(const f32x4*)(zone + 16 + i * 4);
            f32x4 u2 = *(const f32x4*)(zone + 32 + i * 4);
            f32x4 u3 = *(const f32x4*)(zone + 48 + i * 4);
#pragma unroll
            for (int j = 0; j < 4; ++j) {
                oa00[4*i+j] += u0[j]; oa01[4*i+j] += u1[j];
                oa10[4*i+j] += u2[j]; oa11[4*i+j] += u3[j];
            }
        }
        float inv[2];
#pragma unroll
        for (int qt = 0; qt < 2; ++qt) {
            float s = lp[qt] + zone[64 + qt];
            s += __shfl_xor(s, 32);              // opposite g-half's keys
            inv[qt] = 1.0f / s;
        }
        float* op0 = O + ((size_t)(b * 2048 + q0 + nl)) * 1024 + h * 64;
        float* op1 = op0 + 32 * 1024;            // q0 + 32 + nl
#pragma unroll
        for (int rq = 0; rq < 4; ++rq) {
            const int d0 = 8 * rq + 4 * g;
            *(f32x4*)(op0 + d0) = (f32x4){
                oa00[4*rq]   * inv[0], oa00[4*rq+1] * inv[0],
                oa00[4*rq+2] * inv[0], oa00[4*rq+3] * inv[0] };
            *(f32x4*)(op0 + 32 + d0) = (f32x4){
                oa10[4*rq]   * inv[0], oa10[4*rq+1] * inv[0],
                oa10[4*rq+2] * inv[0], oa10[4*rq+3] * inv[0] };
            *(f32x4*)(op1 + d0) = (f32x4){
                oa01[4*rq]   * inv[1], oa01[4*rq+1] * inv[1],
                oa01[4*rq+2] * inv[1], oa01[4*rq+3] * inv[1] };
            *(f32x4*)(op1 + 32 + d0) = (f32x4){
                oa11[4*rq]   * inv[1], oa11[4*rq+1] * inv[1],
                oa11[4*rq+2] * inv[1], oa11[4*rq+3] * inv[1] };
        }
    }
}

extern "C" void kernel_launch(void* const* d_in, const int* in_sizes, int n_in,
                              void* d_out, int out_size, void* d_ws, size_t ws_size,
                              hipStream_t stream) {
    const float* q = (const float*)d_in[0];
    const float* k = (const float*)d_in[1];
    const float* v = (const float*)d_in[2];
    float* o = (float*)d_out;

    unsigned short* Kt = (unsigned short*)d_ws;   // 8 MB fragment-ordered K tiles
    unsigned short* Vt = Kt + 4194304;            // 8 MB fragment-ordered V tiles

    hipLaunchKernelGGL(prep,     dim3(1024), dim3(256), 0, stream, k, v, Kt, Vt);
    hipLaunchKernelGGL(attn_fwd, dim3(512),  dim3(256), 0, stream, q, Kt, Vt, o);
}